// Round 20
// baseline (1341.215 us; speedup 1.0000x reference)
//
#include <hip/hip_runtime.h>
#include <hip/hip_bf16.h>

// Problem constants (B=32, N=256, K=8, D=1024, OUT=1024, HID=2048)
#define ROWS   8192      // B*N
#define DIM    1024      // D
#define XCOLS  3072      // 3*D
#define OUTC   1024
#define HIDC   2048
#define EPS    1e-5f

// ---- DIAGNOSTIC ROUND 2: amplify prep + 3 GEMMs x6 (idempotent) to surface
// ---- per-kernel dur + PMC rows (top-5 bar ~310us). The R19 budget model has
// ---- ~80us unexplained; this arbitrates. Strip next round.
#define PREP_REP 6
#define GM_REP   6

typedef __attribute__((ext_vector_type(8))) short bf16x8;   // 8 bf16 (4 VGPRs)
typedef __attribute__((ext_vector_type(4))) float f32x4;

#define GLOBAL_AS __attribute__((address_space(1)))
#define LDS_AS    __attribute__((address_space(3)))

__device__ __forceinline__ void gll16(const void* g, void* l) {
    __builtin_amdgcn_global_load_lds((const GLOBAL_AS void*)g, (LDS_AS void*)l, 16, 0, 0);
}

__device__ __forceinline__ short f2b(float f) {
    __hip_bfloat16 h = __float2bfloat16(f);
    return *reinterpret_cast<short*>(&h);
}
__device__ __forceinline__ float b2f(short s) {
    unsigned u = ((unsigned)(unsigned short)s) << 16;
    return __uint_as_float(u);
}

// ---------------------------------------------------------------------------
// Merged prep: blocks [0,8192) build_x; [8192,15360) weight transposes.
// ---------------------------------------------------------------------------
__global__ __launch_bounds__(256) void prep(
    const float* __restrict__ selfv, const float* __restrict__ nb,
    const float* __restrict__ mask, __hip_bfloat16* __restrict__ xb,
    const float* __restrict__ Wa, __hip_bfloat16* __restrict__ WaT,
    const float* __restrict__ W1, __hip_bfloat16* __restrict__ W1T,
    const float* __restrict__ W2, __hip_bfloat16* __restrict__ W2T, int nrep)
{
    int tid = threadIdx.x;
    for (int q = 0; q < nrep; ++q) {
    if (blockIdx.x < ROWS) {
        // ---- build_x ----
        int r = blockIdx.x;
        __shared__ float ms[8];
        if (tid < 8) ms[tid] = mask[r * 8 + tid];
        __syncthreads();

        __hip_bfloat16* xr = xb + (size_t)r * XCOLS;
        {
            float4 v = ((const float4*)(selfv + (size_t)r * DIM))[tid];
            short4 o;
            o.x = f2b(v.x); o.y = f2b(v.y); o.z = f2b(v.z); o.w = f2b(v.w);
            *(short4*)&xr[tid * 4] = o;
        }
        const float4* nbase = (const float4*)(nb + (size_t)r * 8 * 2048);
#pragma unroll
        for (int half = 0; half < 2; ++half) {
            int c4 = half * 256 + tid;
            float4 acc = make_float4(0.f, 0.f, 0.f, 0.f);
#pragma unroll
            for (int k = 0; k < 8; ++k) {
                float4 t = nbase[k * 512 + c4];
                float m = ms[k];
                acc.x += t.x * m; acc.y += t.y * m; acc.z += t.z * m; acc.w += t.w * m;
            }
            short4 o;
            o.x = f2b(acc.x * 0.125f); o.y = f2b(acc.y * 0.125f);
            o.z = f2b(acc.z * 0.125f); o.w = f2b(acc.w * 0.125f);
            *(short4*)&xr[1024 + c4 * 4] = o;
        }
        __syncthreads();   // rep fence (ms reload)
    } else {
        // ---- wtrans3 ----
        int b = blockIdx.x - ROWS;
        const float* W; __hip_bfloat16* Wt; int K, N;
        if (b < 3072)      { W = Wa; Wt = WaT; K = 3072; N = 1024; }
        else if (b < 5120) { W = W1; Wt = W1T; K = 1024; N = 2048; b -= 3072; }
        else               { W = W2; Wt = W2T; K = 2048; N = 1024; b -= 5120; }
        int nxb = N >> 5;
        int n0 = (b % nxb) << 5, k0 = (b / nxb) << 5;

        __shared__ float t[32][33];
        int tx = tid & 31, ty = tid >> 5;   // 32 x 8
#pragma unroll
        for (int i = 0; i < 4; ++i)
            t[ty + i * 8][tx] = W[(size_t)(k0 + ty + i * 8) * N + n0 + tx];
        __syncthreads();
#pragma unroll
        for (int i = 0; i < 4; ++i) {
            int n = ty + i * 8;
            Wt[(size_t)(n0 + n) * K + k0 + tx] = __float2bfloat16(t[tx][n]);
        }
        __syncthreads();   // rep fence (t reuse)
    }
    }
}

// ---------------------------------------------------------------------------
// GEMM: R19 kernel + nrep outer repeats (DIAG).
// 128x128 tile, BK=64, 512 threads = 8 waves (2Mx4N), 16x16x32 MFMA,
// acc[4][2], 2 LDS buffers, minimal-sync K-step, coalesced LDS-transpose
// epilogue, both-sides bank swizzle, fused BN partials.
// ---------------------------------------------------------------------------
template <int OUT_BF16, int STATS>
__global__ __launch_bounds__(512) void gemm_bt(
    const short* __restrict__ A, const short* __restrict__ Bt,
    const float* __restrict__ bias, void* __restrict__ Cout,
    float* __restrict__ pS, float* __restrict__ pS2,
    int M, int N, int K, int ntiles, int nrep)
{
    __shared__ short As[2][128 * 64];   // 2 x 16 KB
    __shared__ short Bs[2][128 * 64];   // 2 x 16 KB   (64 KB total)

    int tid = threadIdx.x;              // 0..511
    int lane = tid & 63;
    int w = tid >> 6;                   // 0..7
    int wm = w >> 2, wn = w & 3;        // 2 x 4 wave grid

    int nbn = N >> 7;
    int rowa = (wm << 6) + (lane & 15);
    int rowb = (wn << 5) + (lane & 15);
    int cswz0 = (((lane >> 4) ^ (lane & 7)) << 3);
    int cswz1 = ((((lane >> 4) | 4) ^ (lane & 7)) << 3);
    int lofs = w << 9;
    int c0 = (((tid & 7) ^ ((tid >> 3) & 7)) << 3);

    for (int q = 0; q < nrep; ++q) {
    for (int tix = blockIdx.x; tix < ntiles; tix += gridDim.x) {
        int swz = (tix & 7) * (ntiles >> 3) + (tix >> 3);
        int bm = swz / nbn, bn = swz % nbn;
        int brow = bm << 7, bcol = bn << 7;

        f32x4 acc[4][2] = {};

        const short* gA0 = A + (size_t)(brow + (tid >> 3)) * K + c0;
        const short* gA1 = gA0 + (size_t)64 * K;
        const short* gB0 = Bt + (size_t)(bcol + (tid >> 3)) * K + c0;
        const short* gB1 = gB0 + (size_t)64 * K;

#define STAGE(buf, kk)                                  \
    do {                                                \
        const int buf_ = (buf);                         \
        const int kk_  = (kk);                          \
        gll16(gA0 + kk_, &As[buf_][lofs]);              \
        gll16(gA1 + kk_, &As[buf_][4096 + lofs]);       \
        gll16(gB0 + kk_, &Bs[buf_][lofs]);              \
        gll16(gB1 + kk_, &Bs[buf_][4096 + lofs]);       \
    } while (0)

#define KSTEP(cur, DOSTAGE, SBUF, KKN)                                     \
    do {                                                                   \
        bf16x8 a[4][2], b[2][2];                                           \
        const short* ab = &As[cur][0];                                     \
        const short* bb = &Bs[cur][0];                                     \
        _Pragma("unroll")                                                  \
        for (int m = 0; m < 4; ++m) {                                      \
            int ro = (rowa + (m << 4)) << 6;                               \
            a[m][0] = *(const bf16x8*)&ab[ro + cswz0];                     \
            a[m][1] = *(const bf16x8*)&ab[ro + cswz1];                     \
        }                                                                  \
        _Pragma("unroll")                                                  \
        for (int n = 0; n < 2; ++n) {                                      \
            int ro = (rowb + (n << 4)) << 6;                               \
            b[n][0] = *(const bf16x8*)&bb[ro + cswz0];                     \
            b[n][1] = *(const bf16x8*)&bb[ro + cswz1];                     \
        }                                                                  \
        if (DOSTAGE) STAGE(SBUF, KKN);                                     \
        __builtin_amdgcn_s_setprio(1);                                     \
        _Pragma("unroll")                                                  \
        for (int ks = 0; ks < 2; ++ks) {                                   \
            _Pragma("unroll")                                              \
            for (int m = 0; m < 4; ++m) {                                  \
                _Pragma("unroll")                                          \
                for (int n = 0; n < 2; ++n)                                \
                    acc[m][n] = __builtin_amdgcn_mfma_f32_16x16x32_bf16(   \
                        a[m][ks], b[n][ks], acc[m][n], 0, 0, 0);           \
            }                                                              \
        }                                                                  \
        __builtin_amdgcn_s_setprio(0);                                     \
        asm volatile("s_waitcnt vmcnt(0)" ::: "memory");                   \
        __builtin_amdgcn_s_barrier();                                      \
        __builtin_amdgcn_sched_barrier(0);                                 \
    } while (0)

        int nk = K >> 6;

        STAGE(0, 0);
        asm volatile("s_waitcnt vmcnt(0)" ::: "memory");
        __builtin_amdgcn_s_barrier();
        __builtin_amdgcn_sched_barrier(0);

        for (int i = 0; i < nk; ++i) {
            KSTEP((i & 1), (i + 1 < nk), ((i + 1) & 1), ((i + 1) << 6));
        }
#undef KSTEP
#undef STAGE

        float cs[2] = {0.f, 0.f}, cs2[2] = {0.f, 0.f};
        if (OUT_BF16) {
            // coalesced epilogue: wave-private LDS transpose
            short* tpb = &As[0][0] + (w << 11);
            float bv0 = bias[bcol + (wn << 5) + (lane & 15)];
            float bv1 = bias[bcol + (wn << 5) + 16 + (lane & 15)];
#pragma unroll
            for (int m = 0; m < 4; ++m) {
#pragma unroll
                for (int n = 0; n < 2; ++n) {
                    float bv = n ? bv1 : bv0;
#pragma unroll
                    for (int r = 0; r < 4; ++r) {
                        int row = (m << 4) + ((lane >> 4) << 2) + r;
                        int col = (n << 4) + (lane & 15);
                        float v = acc[m][n][r] + bv;
                        tpb[(row << 5) + col] = f2b(v);
                        if (STATS) { cs[n] += v; cs2[n] += v * v; }
                    }
                }
            }
            asm volatile("s_waitcnt lgkmcnt(0)" ::: "memory");
            __hip_bfloat16* Cb = (__hip_bfloat16*)Cout;
#pragma unroll
            for (int j = 0; j < 4; ++j) {
                int q2 = (j << 6) + lane;
                int row = q2 >> 2, c8 = (q2 & 3) << 3;
                bf16x8 vv = *(const bf16x8*)&tpb[(row << 5) + c8];
                size_t gi = (size_t)(brow + (wm << 6) + row) * N
                            + bcol + (wn << 5) + c8;
                *(bf16x8*)&Cb[gi] = vv;
            }
            __syncthreads();
        } else {
            int crow0 = brow + (wm << 6) + ((lane >> 4) << 2);
            int ccol0 = bcol + (wn << 5) + (lane & 15);
#pragma unroll
            for (int m = 0; m < 4; ++m) {
#pragma unroll
                for (int n = 0; n < 2; ++n) {
                    int col = ccol0 + n * 16;
                    float bv = bias[col];
#pragma unroll
                    for (int r = 0; r < 4; ++r) {
                        int row = crow0 + m * 16 + r;
                        float v = acc[m][n][r] + bv;
                        ((float*)Cout)[(size_t)row * N + col] = v;
                        if (STATS) { cs[n] += v; cs2[n] += v * v; }
                    }
                }
            }
            __syncthreads();
        }

        if (STATS) {
            float* sP = (float*)&As[0][0];
#pragma unroll
            for (int n = 0; n < 2; ++n) {
                float s = cs[n], s2 = cs2[n];
                s  += __shfl_xor(s, 16);  s  += __shfl_xor(s, 32);
                s2 += __shfl_xor(s2, 16); s2 += __shfl_xor(s2, 32);
                if ((lane >> 4) == 0) {
                    int c = (wn << 5) + (n << 4) + (lane & 15);
                    sP[wm * 128 + c] = s;
                    sP[256 + wm * 128 + c] = s2;
                }
            }
            __syncthreads();
            if (tid < 128) {
                float s = sP[tid] + sP[128 + tid];
                float s2 = sP[256 + tid] + sP[384 + tid];
                pS [(size_t)bm * N + bcol + tid] = s;
                pS2[(size_t)bm * N + bcol + tid] = s2;
            }
            __syncthreads();
        }
    }
    }
}

// ---------------------------------------------------------------------------
__global__ __launch_bounds__(256) void bn_stats2(
    const float* __restrict__ pS, const float* __restrict__ pS2,
    const float* __restrict__ g, const float* __restrict__ be,
    float* __restrict__ scale, float* __restrict__ shift, int ncols)
{
    int col = blockIdx.x * 256 + threadIdx.x;
    float s = 0.f, s2 = 0.f;
#pragma unroll
    for (int j = 0; j < 64; ++j) {
        s += pS[j * ncols + col];
        s2 += pS2[j * ncols + col];
    }
    float mu = s * (1.f / 8192.f);
    float var = s2 * (1.f / 8192.f) - mu * mu;
    float rs = rsqrtf(var + EPS);
    float sc = g[col] * rs;
    scale[col] = sc;
    shift[col] = be[col] - mu * sc;
}

__global__ __launch_bounds__(256) void bn_apply_b2b(
    const short* __restrict__ t, const float* __restrict__ scale,
    const float* __restrict__ shift, short* __restrict__ out, int ncols)
{
    size_t i8 = (size_t)blockIdx.x * 256 + threadIdx.x;
    int col0 = (int)((i8 * 8) % ncols);
    bf16x8 v = ((const bf16x8*)t)[i8];
    bf16x8 o;
#pragma unroll
    for (int j = 0; j < 8; ++j) {
        float f = fmaxf(b2f(v[j]) * scale[col0 + j] + shift[col0 + j], 0.f);
        o[j] = f2b(f);
    }
    ((bf16x8*)out)[i8] = o;
}

__global__ __launch_bounds__(256) void bn_apply_b2f(
    const short* __restrict__ t, const float* __restrict__ scale,
    const float* __restrict__ shift, float* __restrict__ out, int ncols)
{
    size_t i8 = (size_t)blockIdx.x * 256 + threadIdx.x;
    int col0 = (int)((i8 * 8) % ncols);
    bf16x8 v = ((const bf16x8*)t)[i8];
    float4 o0, o1;
    o0.x = fmaxf(b2f(v[0]) * scale[col0 + 0] + shift[col0 + 0], 0.f);
    o0.y = fmaxf(b2f(v[1]) * scale[col0 + 1] + shift[col0 + 1], 0.f);
    o0.z = fmaxf(b2f(v[2]) * scale[col0 + 2] + shift[col0 + 2], 0.f);
    o0.w = fmaxf(b2f(v[3]) * scale[col0 + 3] + shift[col0 + 3], 0.f);
    o1.x = fmaxf(b2f(v[4]) * scale[col0 + 4] + shift[col0 + 4], 0.f);
    o1.y = fmaxf(b2f(v[5]) * scale[col0 + 5] + shift[col0 + 5], 0.f);
    o1.z = fmaxf(b2f(v[6]) * scale[col0 + 6] + shift[col0 + 6], 0.f);
    o1.w = fmaxf(b2f(v[7]) * scale[col0 + 7] + shift[col0 + 7], 0.f);
    ((float4*)out)[i8 * 2]     = o0;
    ((float4*)out)[i8 * 2 + 1] = o1;
}

// ---------------------------------------------------------------------------
extern "C" void kernel_launch(void* const* d_in, const int* in_sizes, int n_in,
                              void* d_out, int out_size, void* d_ws, size_t ws_size,
                              hipStream_t stream)
{
    const float* selfv = (const float*)d_in[0];
    const float* nbv   = (const float*)d_in[1];
    const float* mask  = (const float*)d_in[2];
    const float* W_agg = (const float*)d_in[3];
    const float* b_agg = (const float*)d_in[4];
    const float* W1    = (const float*)d_in[5];
    const float* b1    = (const float*)d_in[6];
    const float* g1    = (const float*)d_in[7];
    const float* be1   = (const float*)d_in[8];
    const float* W2    = (const float*)d_in[9];
    const float* b2    = (const float*)d_in[10];
    const float* g2    = (const float*)d_in[11];
    const float* be2   = (const float*)d_in[12];

    char* ws = (char*)d_ws;
    const size_t MiB = 1ull << 20;
    __hip_bfloat16* h    = (__hip_bfloat16*)(ws + 0);
    __hip_bfloat16* xb   = (__hip_bfloat16*)(ws + 16 * MiB);
    __hip_bfloat16* t1b  = (__hip_bfloat16*)(ws + 16 * MiB);
    __hip_bfloat16* h1   = (__hip_bfloat16*)(ws + 80 * MiB);
    __hip_bfloat16* WaggT= (__hip_bfloat16*)(ws + 112 * MiB);
    __hip_bfloat16* W1T  = (__hip_bfloat16*)(ws + 118 * MiB);
    __hip_bfloat16* W2T  = (__hip_bfloat16*)(ws + 122 * MiB);
    float* pS     = (float*)(ws + 126 * MiB);
    float* pS2    = (float*)(ws + 126 * MiB + 512 * 1024);
    float* scale1 = (float*)(ws + 127 * MiB);
    float* shift1 = scale1 + 2048;
    float* scale2 = shift1 + 2048;
    float* shift2 = scale2 + 1024;
    __hip_bfloat16* t2b = h;

    // merged prep [DIAG x PREP_REP]
    prep<<<ROWS + 7168, 256, 0, stream>>>(
        selfv, nbv, mask, xb, W_agg, WaggT, W1, W1T, W2, W2T, PREP_REP);

    // GEMM1 [DIAG x GM_REP]
    gemm_bt<1, 0><<<512, 512, 0, stream>>>(
        (const short*)xb, (const short*)WaggT, b_agg, h, nullptr, nullptr,
        ROWS, OUTC, XCOLS, 512, GM_REP);

    // GEMM2 [DIAG x GM_REP]
    gemm_bt<1, 1><<<1024, 512, 0, stream>>>(
        (const short*)h, (const short*)W1T, b1, t1b, pS, pS2, ROWS, HIDC, OUTC, 1024, GM_REP);

    bn_stats2<<<HIDC / 256, 256, 0, stream>>>(pS, pS2, g1, be1, scale1, shift1, HIDC);
    bn_apply_b2b<<<(ROWS * HIDC) / 2048, 256, 0, stream>>>(
        (const short*)t1b, scale1, shift1, (short*)h1, HIDC);

    // GEMM3 [DIAG x GM_REP]
    gemm_bt<1, 1><<<512, 512, 0, stream>>>(
        (const short*)h1, (const short*)W2T, b2, t2b, pS, pS2, ROWS, OUTC, HIDC, 512, GM_REP);

    bn_stats2<<<OUTC / 256, 256, 0, stream>>>(pS, pS2, g2, be2, scale2, shift2, OUTC);
    bn_apply_b2f<<<(ROWS * OUTC) / 2048, 256, 0, stream>>>(
        (const short*)t2b, scale2, shift2, (float*)d_out, OUTC);
}

// Round 21
// 367.829 us; speedup vs baseline: 3.6463x; 3.6463x over previous
//
#include <hip/hip_runtime.h>
#include <hip/hip_bf16.h>

// Problem constants (B=32, N=256, K=8, D=1024, OUT=1024, HID=2048)
#define ROWS   8192      // B*N
#define DIM    1024      // D
#define XCOLS  3072      // 3*D
#define OUTC   1024
#define HIDC   2048
#define EPS    1e-5f

typedef __attribute__((ext_vector_type(8))) short bf16x8;   // 8 bf16 (4 VGPRs)
typedef __attribute__((ext_vector_type(4))) float f32x4;

#define GLOBAL_AS __attribute__((address_space(1)))
#define LDS_AS    __attribute__((address_space(3)))

__device__ __forceinline__ void gll16(const void* g, void* l) {
    // async global->LDS, 16B per lane; LDS dest = wave-uniform base + lane*16
    __builtin_amdgcn_global_load_lds((const GLOBAL_AS void*)g, (LDS_AS void*)l, 16, 0, 0);
}

__device__ __forceinline__ short f2b(float f) {
    __hip_bfloat16 h = __float2bfloat16(f);
    return *reinterpret_cast<short*>(&h);
}
__device__ __forceinline__ float b2f(short s) {
    unsigned u = ((unsigned)(unsigned short)s) << 16;
    return __uint_as_float(u);
}

// ---------------------------------------------------------------------------
// Merged prep. R21 build_x rewrite (R20 PMC: cold prep latency-throttled at
// ~3.6 TB/s; VGPR=44 forced the 16 entity loads into two serialized batches
// and the per-row LDS-mask __syncthreads blocked cross-row overlap):
//  - masks via 2 lane-uniform float4 loads (L1 broadcast) -- no LDS, no barrier
//  - ALL 17 loads per row issued into named registers before any FMA
//    (~90 VGPR -> 2.1x in-flight bytes)
//  - grid-stride: 2048 blocks x 4 rows (G11), rows overlap freely.
// Blocks [0,2048) build_x; [2048,9216) the three weight transposes.
// Arithmetic order per output element unchanged -> bit-identical results.
// ---------------------------------------------------------------------------
__global__ __launch_bounds__(256) void prep(
    const float* __restrict__ selfv, const float* __restrict__ nb,
    const float* __restrict__ mask, __hip_bfloat16* __restrict__ xb,
    const float* __restrict__ Wa, __hip_bfloat16* __restrict__ WaT,
    const float* __restrict__ W1, __hip_bfloat16* __restrict__ W1T,
    const float* __restrict__ W2, __hip_bfloat16* __restrict__ W2T)
{
    int tid = threadIdx.x;
    if (blockIdx.x < 2048) {
        // ---- build_x: rows bid, bid+2048, bid+4096, bid+6144 ----
#pragma unroll
        for (int j = 0; j < 4; ++j) {
            int r = blockIdx.x + j * 2048;
            const float4* mp = (const float4*)(mask + r * 8);
            float4 mA = mp[0], mB = mp[1];          // lane-uniform (broadcast)
            const float4* nbase = (const float4*)(nb + (size_t)r * 16384);

            // issue ALL loads before any compute
            float4 sv = ((const float4*)(selfv + (size_t)r * DIM))[tid];
            float4 t0[8], t1[8];
#pragma unroll
            for (int k = 0; k < 8; ++k) t0[k] = nbase[k * 512 + tid];
#pragma unroll
            for (int k = 0; k < 8; ++k) t1[k] = nbase[k * 512 + 256 + tid];

            __hip_bfloat16* xr = xb + (size_t)r * XCOLS;
            {
                short4 o;
                o.x = f2b(sv.x); o.y = f2b(sv.y); o.z = f2b(sv.z); o.w = f2b(sv.w);
                *(short4*)&xr[tid * 4] = o;
            }
            float mk[8] = {mA.x, mA.y, mA.z, mA.w, mB.x, mB.y, mB.z, mB.w};
            float4 a0 = make_float4(0.f, 0.f, 0.f, 0.f);
            float4 a1 = make_float4(0.f, 0.f, 0.f, 0.f);
#pragma unroll
            for (int k = 0; k < 8; ++k) {
                a0.x += t0[k].x * mk[k]; a0.y += t0[k].y * mk[k];
                a0.z += t0[k].z * mk[k]; a0.w += t0[k].w * mk[k];
                a1.x += t1[k].x * mk[k]; a1.y += t1[k].y * mk[k];
                a1.z += t1[k].z * mk[k]; a1.w += t1[k].w * mk[k];
            }
            short4 o0, o1;
            o0.x = f2b(a0.x * 0.125f); o0.y = f2b(a0.y * 0.125f);
            o0.z = f2b(a0.z * 0.125f); o0.w = f2b(a0.w * 0.125f);
            o1.x = f2b(a1.x * 0.125f); o1.y = f2b(a1.y * 0.125f);
            o1.z = f2b(a1.z * 0.125f); o1.w = f2b(a1.w * 0.125f);
            *(short4*)&xr[1024 + tid * 4] = o0;
            *(short4*)&xr[2048 + tid * 4] = o1;
        }
    } else {
        // ---- wtrans3 ----
        int b = blockIdx.x - 2048;
        const float* W; __hip_bfloat16* Wt; int K, N;
        if (b < 3072)      { W = Wa; Wt = WaT; K = 3072; N = 1024; }
        else if (b < 5120) { W = W1; Wt = W1T; K = 1024; N = 2048; b -= 3072; }
        else               { W = W2; Wt = W2T; K = 2048; N = 1024; b -= 5120; }
        int nxb = N >> 5;
        int n0 = (b % nxb) << 5, k0 = (b / nxb) << 5;

        __shared__ float t[32][33];
        int tx = tid & 31, ty = tid >> 5;   // 32 x 8
#pragma unroll
        for (int i = 0; i < 4; ++i)
            t[ty + i * 8][tx] = W[(size_t)(k0 + ty + i * 8) * N + n0 + tx];
        __syncthreads();
#pragma unroll
        for (int i = 0; i < 4; ++i) {
            int n = ty + i * 8;
            Wt[(size_t)(n0 + n) * K + k0 + tx] = __float2bfloat16(t[tx][n]);
        }
    }
}

// ---------------------------------------------------------------------------
// GEMM: C[M,N] = A[M,K] @ Bt[N,K]^T + bias   (bf16 in, f32 acc)
// R19 kernel (best measured): 128x128 tile, BK=64, 512 threads = 8 waves
// (2Mx4N, wave tile 64x32), 16x16x32 MFMA, acc[4][2], 2 LDS buffers,
// minimal-sync K-step {ds_read||stage -> MFMA -> vmcnt(0) -> barrier},
// coalesced LDS-transpose epilogue, both-sides bank swizzle (conflicts=0),
// fused BN partials.
// ---------------------------------------------------------------------------
template <int OUT_BF16, int STATS>
__global__ __launch_bounds__(512) void gemm_bt(
    const short* __restrict__ A, const short* __restrict__ Bt,
    const float* __restrict__ bias, void* __restrict__ Cout,
    float* __restrict__ pS, float* __restrict__ pS2,
    int M, int N, int K, int ntiles)
{
    __shared__ short As[2][128 * 64];   // 2 x 16 KB
    __shared__ short Bs[2][128 * 64];   // 2 x 16 KB   (64 KB total)

    int tid = threadIdx.x;              // 0..511
    int lane = tid & 63;
    int w = tid >> 6;                   // 0..7
    int wm = w >> 2, wn = w & 3;        // 2 x 4 wave grid

    int nbn = N >> 7;
    int rowa = (wm << 6) + (lane & 15);
    int rowb = (wn << 5) + (lane & 15);
    int cswz0 = (((lane >> 4) ^ (lane & 7)) << 3);
    int cswz1 = ((((lane >> 4) | 4) ^ (lane & 7)) << 3);
    int lofs = w << 9;
    int c0 = (((tid & 7) ^ ((tid >> 3) & 7)) << 3);

    for (int tix = blockIdx.x; tix < ntiles; tix += gridDim.x) {
        int swz = (tix & 7) * (ntiles >> 3) + (tix >> 3);
        int bm = swz / nbn, bn = swz % nbn;
        int brow = bm << 7, bcol = bn << 7;

        f32x4 acc[4][2] = {};

        const short* gA0 = A + (size_t)(brow + (tid >> 3)) * K + c0;
        const short* gA1 = gA0 + (size_t)64 * K;
        const short* gB0 = Bt + (size_t)(bcol + (tid >> 3)) * K + c0;
        const short* gB1 = gB0 + (size_t)64 * K;

#define STAGE(buf, kk)                                  \
    do {                                                \
        const int buf_ = (buf);                         \
        const int kk_  = (kk);                          \
        gll16(gA0 + kk_, &As[buf_][lofs]);              \
        gll16(gA1 + kk_, &As[buf_][4096 + lofs]);       \
        gll16(gB0 + kk_, &Bs[buf_][lofs]);              \
        gll16(gB1 + kk_, &Bs[buf_][4096 + lofs]);       \
    } while (0)

#define KSTEP(cur, DOSTAGE, SBUF, KKN)                                     \
    do {                                                                   \
        bf16x8 a[4][2], b[2][2];                                           \
        const short* ab = &As[cur][0];                                     \
        const short* bb = &Bs[cur][0];                                     \
        _Pragma("unroll")                                                  \
        for (int m = 0; m < 4; ++m) {                                      \
            int ro = (rowa + (m << 4)) << 6;                               \
            a[m][0] = *(const bf16x8*)&ab[ro + cswz0];                     \
            a[m][1] = *(const bf16x8*)&ab[ro + cswz1];                     \
        }                                                                  \
        _Pragma("unroll")                                                  \
        for (int n = 0; n < 2; ++n) {                                      \
            int ro = (rowb + (n << 4)) << 6;                               \
            b[n][0] = *(const bf16x8*)&bb[ro + cswz0];                     \
            b[n][1] = *(const bf16x8*)&bb[ro + cswz1];                     \
        }                                                                  \
        if (DOSTAGE) STAGE(SBUF, KKN);                                     \
        __builtin_amdgcn_s_setprio(1);                                     \
        _Pragma("unroll")                                                  \
        for (int ks = 0; ks < 2; ++ks) {                                   \
            _Pragma("unroll")                                              \
            for (int m = 0; m < 4; ++m) {                                  \
                _Pragma("unroll")                                          \
                for (int n = 0; n < 2; ++n)                                \
                    acc[m][n] = __builtin_amdgcn_mfma_f32_16x16x32_bf16(   \
                        a[m][ks], b[n][ks], acc[m][n], 0, 0, 0);           \
            }                                                              \
        }                                                                  \
        __builtin_amdgcn_s_setprio(0);                                     \
        asm volatile("s_waitcnt vmcnt(0)" ::: "memory");                   \
        __builtin_amdgcn_s_barrier();                                      \
        __builtin_amdgcn_sched_barrier(0);                                 \
    } while (0)

        int nk = K >> 6;

        STAGE(0, 0);
        asm volatile("s_waitcnt vmcnt(0)" ::: "memory");
        __builtin_amdgcn_s_barrier();
        __builtin_amdgcn_sched_barrier(0);

        for (int i = 0; i < nk; ++i) {
            KSTEP((i & 1), (i + 1 < nk), ((i + 1) & 1), ((i + 1) << 6));
        }
#undef KSTEP
#undef STAGE

        float cs[2] = {0.f, 0.f}, cs2[2] = {0.f, 0.f};
        if (OUT_BF16) {
            // coalesced epilogue: wave-private LDS transpose
            short* tpb = &As[0][0] + (w << 11);
            float bv0 = bias[bcol + (wn << 5) + (lane & 15)];
            float bv1 = bias[bcol + (wn << 5) + 16 + (lane & 15)];
#pragma unroll
            for (int m = 0; m < 4; ++m) {
#pragma unroll
                for (int n = 0; n < 2; ++n) {
                    float bv = n ? bv1 : bv0;
#pragma unroll
                    for (int r = 0; r < 4; ++r) {
                        int row = (m << 4) + ((lane >> 4) << 2) + r;
                        int col = (n << 4) + (lane & 15);
                        float v = acc[m][n][r] + bv;
                        tpb[(row << 5) + col] = f2b(v);
                        if (STATS) { cs[n] += v; cs2[n] += v * v; }
                    }
                }
            }
            asm volatile("s_waitcnt lgkmcnt(0)" ::: "memory");
            __hip_bfloat16* Cb = (__hip_bfloat16*)Cout;
#pragma unroll
            for (int j = 0; j < 4; ++j) {
                int q2 = (j << 6) + lane;
                int row = q2 >> 2, c8 = (q2 & 3) << 3;
                bf16x8 vv = *(const bf16x8*)&tpb[(row << 5) + c8];
                size_t gi = (size_t)(brow + (wm << 6) + row) * N
                            + bcol + (wn << 5) + c8;
                *(bf16x8*)&Cb[gi] = vv;
            }
            __syncthreads();
        } else {
            int crow0 = brow + (wm << 6) + ((lane >> 4) << 2);
            int ccol0 = bcol + (wn << 5) + (lane & 15);
#pragma unroll
            for (int m = 0; m < 4; ++m) {
#pragma unroll
                for (int n = 0; n < 2; ++n) {
                    int col = ccol0 + n * 16;
                    float bv = bias[col];
#pragma unroll
                    for (int r = 0; r < 4; ++r) {
                        int row = crow0 + m * 16 + r;
                        float v = acc[m][n][r] + bv;
                        ((float*)Cout)[(size_t)row * N + col] = v;
                        if (STATS) { cs[n] += v; cs2[n] += v * v; }
                    }
                }
            }
            __syncthreads();
        }

        if (STATS) {
            float* sP = (float*)&As[0][0];
#pragma unroll
            for (int n = 0; n < 2; ++n) {
                float s = cs[n], s2 = cs2[n];
                s  += __shfl_xor(s, 16);  s  += __shfl_xor(s, 32);
                s2 += __shfl_xor(s2, 16); s2 += __shfl_xor(s2, 32);
                if ((lane >> 4) == 0) {
                    int c = (wn << 5) + (n << 4) + (lane & 15);
                    sP[wm * 128 + c] = s;
                    sP[256 + wm * 128 + c] = s2;
                }
            }
            __syncthreads();
            if (tid < 128) {
                float s = sP[tid] + sP[128 + tid];
                float s2 = sP[256 + tid] + sP[384 + tid];
                pS [(size_t)bm * N + bcol + tid] = s;
                pS2[(size_t)bm * N + bcol + tid] = s2;
            }
            __syncthreads();
        }
    }
}

// ---------------------------------------------------------------------------
// BN stats reduce: 64 row-chunk partials -> per-column scale/shift
// ---------------------------------------------------------------------------
__global__ __launch_bounds__(256) void bn_stats2(
    const float* __restrict__ pS, const float* __restrict__ pS2,
    const float* __restrict__ g, const float* __restrict__ be,
    float* __restrict__ scale, float* __restrict__ shift, int ncols)
{
    int col = blockIdx.x * 256 + threadIdx.x;
    float s = 0.f, s2 = 0.f;
#pragma unroll
    for (int j = 0; j < 64; ++j) {
        s += pS[j * ncols + col];
        s2 += pS2[j * ncols + col];
    }
    float mu = s * (1.f / 8192.f);
    float var = s2 * (1.f / 8192.f) - mu * mu;
    float rs = rsqrtf(var + EPS);
    float sc = g[col] * rs;
    scale[col] = sc;
    shift[col] = be[col] - mu * sc;
}

// BN apply + ReLU, bf16 in -> bf16 out (hidden activation)
__global__ __launch_bounds__(256) void bn_apply_b2b(
    const short* __restrict__ t, const float* __restrict__ scale,
    const float* __restrict__ shift, short* __restrict__ out, int ncols)
{
    size_t i8 = (size_t)blockIdx.x * 256 + threadIdx.x;
    int col0 = (int)((i8 * 8) % ncols);
    bf16x8 v = ((const bf16x8*)t)[i8];
    bf16x8 o;
#pragma unroll
    for (int j = 0; j < 8; ++j) {
        float f = fmaxf(b2f(v[j]) * scale[col0 + j] + shift[col0 + j], 0.f);
        o[j] = f2b(f);
    }
    ((bf16x8*)out)[i8] = o;
}

// BN apply + ReLU, bf16 in -> f32 out (final, into d_out)
__global__ __launch_bounds__(256) void bn_apply_b2f(
    const short* __restrict__ t, const float* __restrict__ scale,
    const float* __restrict__ shift, float* __restrict__ out, int ncols)
{
    size_t i8 = (size_t)blockIdx.x * 256 + threadIdx.x;
    int col0 = (int)((i8 * 8) % ncols);
    bf16x8 v = ((const bf16x8*)t)[i8];
    float4 o0, o1;
    o0.x = fmaxf(b2f(v[0]) * scale[col0 + 0] + shift[col0 + 0], 0.f);
    o0.y = fmaxf(b2f(v[1]) * scale[col0 + 1] + shift[col0 + 1], 0.f);
    o0.z = fmaxf(b2f(v[2]) * scale[col0 + 2] + shift[col0 + 2], 0.f);
    o0.w = fmaxf(b2f(v[3]) * scale[col0 + 3] + shift[col0 + 3], 0.f);
    o1.x = fmaxf(b2f(v[4]) * scale[col0 + 4] + shift[col0 + 4], 0.f);
    o1.y = fmaxf(b2f(v[5]) * scale[col0 + 5] + shift[col0 + 5], 0.f);
    o1.z = fmaxf(b2f(v[6]) * scale[col0 + 6] + shift[col0 + 6], 0.f);
    o1.w = fmaxf(b2f(v[7]) * scale[col0 + 7] + shift[col0 + 7], 0.f);
    ((float4*)out)[i8 * 2]     = o0;
    ((float4*)out)[i8 * 2 + 1] = o1;
}

// ---------------------------------------------------------------------------
extern "C" void kernel_launch(void* const* d_in, const int* in_sizes, int n_in,
                              void* d_out, int out_size, void* d_ws, size_t ws_size,
                              hipStream_t stream)
{
    const float* selfv = (const float*)d_in[0];   // [32,256,1024]
    const float* nbv   = (const float*)d_in[1];   // [32,256,8,2048]
    const float* mask  = (const float*)d_in[2];   // [32,256,8,1]
    const float* W_agg = (const float*)d_in[3];   // [3072,1024]
    const float* b_agg = (const float*)d_in[4];   // [1024]
    const float* W1    = (const float*)d_in[5];   // [1024,2048]
    const float* b1    = (const float*)d_in[6];   // [2048]
    const float* g1    = (const float*)d_in[7];
    const float* be1   = (const float*)d_in[8];
    const float* W2    = (const float*)d_in[9];   // [2048,1024]
    const float* b2    = (const float*)d_in[10];
    const float* g2    = (const float*)d_in[11];
    const float* be2   = (const float*)d_in[12];

    char* ws = (char*)d_ws;
    const size_t MiB = 1ull << 20;
    __hip_bfloat16* h    = (__hip_bfloat16*)(ws + 0);          // [8192,1024] bf16, 16 MiB
    __hip_bfloat16* xb   = (__hip_bfloat16*)(ws + 16 * MiB);   // [8192,3072] bf16, 48 MiB
    __hip_bfloat16* t1b  = (__hip_bfloat16*)(ws + 16 * MiB);   // [8192,2048] bf16, 32 MiB
    __hip_bfloat16* h1   = (__hip_bfloat16*)(ws + 80 * MiB);   // [8192,2048] bf16, 32 MiB
    __hip_bfloat16* WaggT= (__hip_bfloat16*)(ws + 112 * MiB);  // [1024,3072] bf16, 6 MiB
    __hip_bfloat16* W1T  = (__hip_bfloat16*)(ws + 118 * MiB);  // [2048,1024] bf16, 4 MiB
    __hip_bfloat16* W2T  = (__hip_bfloat16*)(ws + 122 * MiB);  // [1024,2048] bf16, 4 MiB
    float* pS     = (float*)(ws + 126 * MiB);                   // [64,2048] partials
    float* pS2    = (float*)(ws + 126 * MiB + 512 * 1024);
    float* scale1 = (float*)(ws + 127 * MiB);
    float* shift1 = scale1 + 2048;
    float* scale2 = shift1 + 2048;
    float* shift2 = scale2 + 1024;
    __hip_bfloat16* t2b = h;   // [8192,1024] bf16 (h is dead after GEMM2)

    // merged prep: build_x (2048 grid-stride blocks) + 3 weight transposes
    prep<<<2048 + 7168, 256, 0, stream>>>(
        selfv, nbv, mask, xb, W_agg, WaggT, W1, W1T, W2, W2T);

    // GEMM1: h = x @ W_agg + b_agg   (bf16 out, no stats)
    gemm_bt<1, 0><<<512, 512, 0, stream>>>(
        (const short*)xb, (const short*)WaggT, b_agg, h, nullptr, nullptr,
        ROWS, OUTC, XCOLS, 512);

    // GEMM2: t1b = h @ W1 + b1  (bf16 out + BN1 partials)
    gemm_bt<1, 1><<<1024, 512, 0, stream>>>(
        (const short*)h, (const short*)W1T, b1, t1b, pS, pS2, ROWS, HIDC, OUTC, 1024);

    // BN1 reduce + apply + ReLU -> h1 (bf16)
    bn_stats2<<<HIDC / 256, 256, 0, stream>>>(pS, pS2, g1, be1, scale1, shift1, HIDC);
    bn_apply_b2b<<<(ROWS * HIDC) / 2048, 256, 0, stream>>>(
        (const short*)t1b, scale1, shift1, (short*)h1, HIDC);

    // GEMM3: t2b = h1 @ W2 + b2  (bf16 out + BN2 partials)
    gemm_bt<1, 1><<<512, 512, 0, stream>>>(
        (const short*)h1, (const short*)W2T, b2, t2b, pS, pS2, ROWS, OUTC, HIDC, 512);

    // BN2 reduce + apply + ReLU -> d_out (f32)
    bn_stats2<<<OUTC / 256, 256, 0, stream>>>(pS, pS2, g2, be2, scale2, shift2, OUTC);
    bn_apply_b2f<<<(ROWS * OUTC) / 2048, 256, 0, stream>>>(
        (const short*)t2b, scale2, shift2, (float*)d_out, OUTC);
}

// Round 22
// 364.284 us; speedup vs baseline: 3.6818x; 1.0097x over previous
//
#include <hip/hip_runtime.h>
#include <hip/hip_bf16.h>

// Problem constants (B=32, N=256, K=8, D=1024, OUT=1024, HID=2048)
#define ROWS   8192      // B*N
#define DIM    1024      // D
#define XCOLS  3072      // 3*D
#define OUTC   1024
#define HIDC   2048
#define EPS    1e-5f

typedef __attribute__((ext_vector_type(8))) short bf16x8;   // 8 bf16 (4 VGPRs)
typedef __attribute__((ext_vector_type(4))) float f32x4;

#define GLOBAL_AS __attribute__((address_space(1)))
#define LDS_AS    __attribute__((address_space(3)))

__device__ __forceinline__ void gll16(const void* g, void* l) {
    // async global->LDS, 16B per lane; LDS dest = wave-uniform base + lane*16
    __builtin_amdgcn_global_load_lds((const GLOBAL_AS void*)g, (LDS_AS void*)l, 16, 0, 0);
}

__device__ __forceinline__ short f2b(float f) {
    __hip_bfloat16 h = __float2bfloat16(f);
    return *reinterpret_cast<short*>(&h);
}
__device__ __forceinline__ float b2f(short s) {
    unsigned u = ((unsigned)(unsigned short)s) << 16;
    return __uint_as_float(u);
}

// ---------------------------------------------------------------------------
// Merged prep (one launch, overlapped): blocks [0,8192) do build_x;
// blocks [8192,15360) do the three weight transposes (f32 -> bf16, K-major).
// (R21's load-parallelism rewrite of build_x was null -> R19 form retained.)
// ---------------------------------------------------------------------------
__global__ __launch_bounds__(256) void prep(
    const float* __restrict__ selfv, const float* __restrict__ nb,
    const float* __restrict__ mask, __hip_bfloat16* __restrict__ xb,
    const float* __restrict__ Wa, __hip_bfloat16* __restrict__ WaT,
    const float* __restrict__ W1, __hip_bfloat16* __restrict__ W1T,
    const float* __restrict__ W2, __hip_bfloat16* __restrict__ W2T)
{
    int tid = threadIdx.x;
    if (blockIdx.x < ROWS) {
        // ---- build_x ----
        int r = blockIdx.x;
        __shared__ float ms[8];
        if (tid < 8) ms[tid] = mask[r * 8 + tid];
        __syncthreads();

        __hip_bfloat16* xr = xb + (size_t)r * XCOLS;
        {
            float4 v = ((const float4*)(selfv + (size_t)r * DIM))[tid];
            short4 o;
            o.x = f2b(v.x); o.y = f2b(v.y); o.z = f2b(v.z); o.w = f2b(v.w);
            *(short4*)&xr[tid * 4] = o;
        }
        const float4* nbase = (const float4*)(nb + (size_t)r * 8 * 2048);
#pragma unroll
        for (int half = 0; half < 2; ++half) {
            int c4 = half * 256 + tid;
            float4 acc = make_float4(0.f, 0.f, 0.f, 0.f);
#pragma unroll
            for (int k = 0; k < 8; ++k) {
                float4 t = nbase[k * 512 + c4];
                float m = ms[k];
                acc.x += t.x * m; acc.y += t.y * m; acc.z += t.z * m; acc.w += t.w * m;
            }
            short4 o;
            o.x = f2b(acc.x * 0.125f); o.y = f2b(acc.y * 0.125f);
            o.z = f2b(acc.z * 0.125f); o.w = f2b(acc.w * 0.125f);
            *(short4*)&xr[1024 + c4 * 4] = o;
        }
    } else {
        // ---- wtrans3 ----
        int b = blockIdx.x - ROWS;
        const float* W; __hip_bfloat16* Wt; int K, N;
        if (b < 3072)      { W = Wa; Wt = WaT; K = 3072; N = 1024; }
        else if (b < 5120) { W = W1; Wt = W1T; K = 1024; N = 2048; b -= 3072; }
        else               { W = W2; Wt = W2T; K = 2048; N = 1024; b -= 5120; }
        int nxb = N >> 5;
        int n0 = (b % nxb) << 5, k0 = (b / nxb) << 5;

        __shared__ float t[32][33];
        int tx = tid & 31, ty = tid >> 5;   // 32 x 8
#pragma unroll
        for (int i = 0; i < 4; ++i)
            t[ty + i * 8][tx] = W[(size_t)(k0 + ty + i * 8) * N + n0 + tx];
        __syncthreads();
#pragma unroll
        for (int i = 0; i < 4; ++i) {
            int n = ty + i * 8;
            Wt[(size_t)(n0 + n) * K + k0 + tx] = __float2bfloat16(t[tx][n]);
        }
    }
}

// ---------------------------------------------------------------------------
// GEMM: C[M,N] = A[M,K] @ Bt[N,K]^T + bias   (bf16 in, f32 acc)
// R19 kernel (best measured 364.6us total): 128x128 tile, BK=64, 512 threads
// = 8 waves (2Mx4N, wave tile 64x32), 16x16x32 MFMA, acc[4][2], 2 LDS
// buffers, minimal-sync K-step {ds_read||stage -> MFMA -> vmcnt(0) ->
// barrier}, coalesced LDS-transpose epilogue, both-sides bank swizzle
// (R9-verified: conflicts 3.8e7 -> 0), fused BN partials.
// R22: GEMM2 launched with grid=512 (2 tiles/block persistent) -- at 64KB
// LDS only 2 blocks/CU are resident, so grid=1024 ran as two dispatch
// rounds; persistence amortizes one prologue+epilogue pair.
// ---------------------------------------------------------------------------
template <int OUT_BF16, int STATS>
__global__ __launch_bounds__(512) void gemm_bt(
    const short* __restrict__ A, const short* __restrict__ Bt,
    const float* __restrict__ bias, void* __restrict__ Cout,
    float* __restrict__ pS, float* __restrict__ pS2,
    int M, int N, int K, int ntiles)
{
    __shared__ short As[2][128 * 64];   // 2 x 16 KB
    __shared__ short Bs[2][128 * 64];   // 2 x 16 KB   (64 KB total)

    int tid = threadIdx.x;              // 0..511
    int lane = tid & 63;
    int w = tid >> 6;                   // 0..7
    int wm = w >> 2, wn = w & 3;        // 2 x 4 wave grid

    int nbn = N >> 7;
    int rowa = (wm << 6) + (lane & 15);
    int rowb = (wn << 5) + (lane & 15);
    int cswz0 = (((lane >> 4) ^ (lane & 7)) << 3);
    int cswz1 = ((((lane >> 4) | 4) ^ (lane & 7)) << 3);
    int lofs = w << 9;
    int c0 = (((tid & 7) ^ ((tid >> 3) & 7)) << 3);

    for (int tix = blockIdx.x; tix < ntiles; tix += gridDim.x) {
        int swz = (tix & 7) * (ntiles >> 3) + (tix >> 3);
        int bm = swz / nbn, bn = swz % nbn;
        int brow = bm << 7, bcol = bn << 7;

        f32x4 acc[4][2] = {};

        const short* gA0 = A + (size_t)(brow + (tid >> 3)) * K + c0;
        const short* gA1 = gA0 + (size_t)64 * K;
        const short* gB0 = Bt + (size_t)(bcol + (tid >> 3)) * K + c0;
        const short* gB1 = gB0 + (size_t)64 * K;

#define STAGE(buf, kk)                                  \
    do {                                                \
        const int buf_ = (buf);                         \
        const int kk_  = (kk);                          \
        gll16(gA0 + kk_, &As[buf_][lofs]);              \
        gll16(gA1 + kk_, &As[buf_][4096 + lofs]);       \
        gll16(gB0 + kk_, &Bs[buf_][lofs]);              \
        gll16(gB1 + kk_, &Bs[buf_][4096 + lofs]);       \
    } while (0)

#define KSTEP(cur, DOSTAGE, SBUF, KKN)                                     \
    do {                                                                   \
        bf16x8 a[4][2], b[2][2];                                           \
        const short* ab = &As[cur][0];                                     \
        const short* bb = &Bs[cur][0];                                     \
        _Pragma("unroll")                                                  \
        for (int m = 0; m < 4; ++m) {                                      \
            int ro = (rowa + (m << 4)) << 6;                               \
            a[m][0] = *(const bf16x8*)&ab[ro + cswz0];                     \
            a[m][1] = *(const bf16x8*)&ab[ro + cswz1];                     \
        }                                                                  \
        _Pragma("unroll")                                                  \
        for (int n = 0; n < 2; ++n) {                                      \
            int ro = (rowb + (n << 4)) << 6;                               \
            b[n][0] = *(const bf16x8*)&bb[ro + cswz0];                     \
            b[n][1] = *(const bf16x8*)&bb[ro + cswz1];                     \
        }                                                                  \
        if (DOSTAGE) STAGE(SBUF, KKN);                                     \
        __builtin_amdgcn_s_setprio(1);                                     \
        _Pragma("unroll")                                                  \
        for (int ks = 0; ks < 2; ++ks) {                                   \
            _Pragma("unroll")                                              \
            for (int m = 0; m < 4; ++m) {                                  \
                _Pragma("unroll")                                          \
                for (int n = 0; n < 2; ++n)                                \
                    acc[m][n] = __builtin_amdgcn_mfma_f32_16x16x32_bf16(   \
                        a[m][ks], b[n][ks], acc[m][n], 0, 0, 0);           \
            }                                                              \
        }                                                                  \
        __builtin_amdgcn_s_setprio(0);                                     \
        asm volatile("s_waitcnt vmcnt(0)" ::: "memory");                   \
        __builtin_amdgcn_s_barrier();                                      \
        __builtin_amdgcn_sched_barrier(0);                                 \
    } while (0)

        int nk = K >> 6;

        STAGE(0, 0);
        asm volatile("s_waitcnt vmcnt(0)" ::: "memory");
        __builtin_amdgcn_s_barrier();
        __builtin_amdgcn_sched_barrier(0);

        for (int i = 0; i < nk; ++i) {
            KSTEP((i & 1), (i + 1 < nk), ((i + 1) & 1), ((i + 1) << 6));
        }
#undef KSTEP
#undef STAGE

        float cs[2] = {0.f, 0.f}, cs2[2] = {0.f, 0.f};
        if (OUT_BF16) {
            // coalesced epilogue: wave-private LDS transpose
            short* tpb = &As[0][0] + (w << 11);
            float bv0 = bias[bcol + (wn << 5) + (lane & 15)];
            float bv1 = bias[bcol + (wn << 5) + 16 + (lane & 15)];
#pragma unroll
            for (int m = 0; m < 4; ++m) {
#pragma unroll
                for (int n = 0; n < 2; ++n) {
                    float bv = n ? bv1 : bv0;
#pragma unroll
                    for (int r = 0; r < 4; ++r) {
                        int row = (m << 4) + ((lane >> 4) << 2) + r;
                        int col = (n << 4) + (lane & 15);
                        float v = acc[m][n][r] + bv;
                        tpb[(row << 5) + col] = f2b(v);
                        if (STATS) { cs[n] += v; cs2[n] += v * v; }
                    }
                }
            }
            asm volatile("s_waitcnt lgkmcnt(0)" ::: "memory");
            __hip_bfloat16* Cb = (__hip_bfloat16*)Cout;
#pragma unroll
            for (int j = 0; j < 4; ++j) {
                int q2 = (j << 6) + lane;
                int row = q2 >> 2, c8 = (q2 & 3) << 3;
                bf16x8 vv = *(const bf16x8*)&tpb[(row << 5) + c8];
                size_t gi = (size_t)(brow + (wm << 6) + row) * N
                            + bcol + (wn << 5) + c8;
                *(bf16x8*)&Cb[gi] = vv;
            }
            __syncthreads();
        } else {
            int crow0 = brow + (wm << 6) + ((lane >> 4) << 2);
            int ccol0 = bcol + (wn << 5) + (lane & 15);
#pragma unroll
            for (int m = 0; m < 4; ++m) {
#pragma unroll
                for (int n = 0; n < 2; ++n) {
                    int col = ccol0 + n * 16;
                    float bv = bias[col];
#pragma unroll
                    for (int r = 0; r < 4; ++r) {
                        int row = crow0 + m * 16 + r;
                        float v = acc[m][n][r] + bv;
                        ((float*)Cout)[(size_t)row * N + col] = v;
                        if (STATS) { cs[n] += v; cs2[n] += v * v; }
                    }
                }
            }
            __syncthreads();
        }

        if (STATS) {
            float* sP = (float*)&As[0][0];
#pragma unroll
            for (int n = 0; n < 2; ++n) {
                float s = cs[n], s2 = cs2[n];
                s  += __shfl_xor(s, 16);  s  += __shfl_xor(s, 32);
                s2 += __shfl_xor(s2, 16); s2 += __shfl_xor(s2, 32);
                if ((lane >> 4) == 0) {
                    int c = (wn << 5) + (n << 4) + (lane & 15);
                    sP[wm * 128 + c] = s;
                    sP[256 + wm * 128 + c] = s2;
                }
            }
            __syncthreads();
            if (tid < 128) {
                float s = sP[tid] + sP[128 + tid];
                float s2 = sP[256 + tid] + sP[384 + tid];
                pS [(size_t)bm * N + bcol + tid] = s;
                pS2[(size_t)bm * N + bcol + tid] = s2;
            }
            __syncthreads();
        }
    }
}

// ---------------------------------------------------------------------------
// BN stats reduce: 64 row-chunk partials -> per-column scale/shift
// ---------------------------------------------------------------------------
__global__ __launch_bounds__(256) void bn_stats2(
    const float* __restrict__ pS, const float* __restrict__ pS2,
    const float* __restrict__ g, const float* __restrict__ be,
    float* __restrict__ scale, float* __restrict__ shift, int ncols)
{
    int col = blockIdx.x * 256 + threadIdx.x;
    float s = 0.f, s2 = 0.f;
#pragma unroll
    for (int j = 0; j < 64; ++j) {
        s += pS[j * ncols + col];
        s2 += pS2[j * ncols + col];
    }
    float mu = s * (1.f / 8192.f);
    float var = s2 * (1.f / 8192.f) - mu * mu;
    float rs = rsqrtf(var + EPS);
    float sc = g[col] * rs;
    scale[col] = sc;
    shift[col] = be[col] - mu * sc;
}

// BN apply + ReLU, bf16 in -> bf16 out (hidden activation)
__global__ __launch_bounds__(256) void bn_apply_b2b(
    const short* __restrict__ t, const float* __restrict__ scale,
    const float* __restrict__ shift, short* __restrict__ out, int ncols)
{
    size_t i8 = (size_t)blockIdx.x * 256 + threadIdx.x;
    int col0 = (int)((i8 * 8) % ncols);
    bf16x8 v = ((const bf16x8*)t)[i8];
    bf16x8 o;
#pragma unroll
    for (int j = 0; j < 8; ++j) {
        float f = fmaxf(b2f(v[j]) * scale[col0 + j] + shift[col0 + j], 0.f);
        o[j] = f2b(f);
    }
    ((bf16x8*)out)[i8] = o;
}

// BN apply + ReLU, bf16 in -> f32 out (final, into d_out)
__global__ __launch_bounds__(256) void bn_apply_b2f(
    const short* __restrict__ t, const float* __restrict__ scale,
    const float* __restrict__ shift, float* __restrict__ out, int ncols)
{
    size_t i8 = (size_t)blockIdx.x * 256 + threadIdx.x;
    int col0 = (int)((i8 * 8) % ncols);
    bf16x8 v = ((const bf16x8*)t)[i8];
    float4 o0, o1;
    o0.x = fmaxf(b2f(v[0]) * scale[col0 + 0] + shift[col0 + 0], 0.f);
    o0.y = fmaxf(b2f(v[1]) * scale[col0 + 1] + shift[col0 + 1], 0.f);
    o0.z = fmaxf(b2f(v[2]) * scale[col0 + 2] + shift[col0 + 2], 0.f);
    o0.w = fmaxf(b2f(v[3]) * scale[col0 + 3] + shift[col0 + 3], 0.f);
    o1.x = fmaxf(b2f(v[4]) * scale[col0 + 4] + shift[col0 + 4], 0.f);
    o1.y = fmaxf(b2f(v[5]) * scale[col0 + 5] + shift[col0 + 5], 0.f);
    o1.z = fmaxf(b2f(v[6]) * scale[col0 + 6] + shift[col0 + 6], 0.f);
    o1.w = fmaxf(b2f(v[7]) * scale[col0 + 7] + shift[col0 + 7], 0.f);
    ((float4*)out)[i8 * 2]     = o0;
    ((float4*)out)[i8 * 2 + 1] = o1;
}

// ---------------------------------------------------------------------------
extern "C" void kernel_launch(void* const* d_in, const int* in_sizes, int n_in,
                              void* d_out, int out_size, void* d_ws, size_t ws_size,
                              hipStream_t stream)
{
    const float* selfv = (const float*)d_in[0];   // [32,256,1024]
    const float* nbv   = (const float*)d_in[1];   // [32,256,8,2048]
    const float* mask  = (const float*)d_in[2];   // [32,256,8,1]
    const float* W_agg = (const float*)d_in[3];   // [3072,1024]
    const float* b_agg = (const float*)d_in[4];   // [1024]
    const float* W1    = (const float*)d_in[5];   // [1024,2048]
    const float* b1    = (const float*)d_in[6];   // [2048]
    const float* g1    = (const float*)d_in[7];
    const float* be1   = (const float*)d_in[8];
    const float* W2    = (const float*)d_in[9];   // [2048,1024]
    const float* b2    = (const float*)d_in[10];
    const float* g2    = (const float*)d_in[11];
    const float* be2   = (const float*)d_in[12];

    char* ws = (char*)d_ws;
    const size_t MiB = 1ull << 20;
    __hip_bfloat16* h    = (__hip_bfloat16*)(ws + 0);          // [8192,1024] bf16, 16 MiB
    __hip_bfloat16* xb   = (__hip_bfloat16*)(ws + 16 * MiB);   // [8192,3072] bf16, 48 MiB
    __hip_bfloat16* t1b  = (__hip_bfloat16*)(ws + 16 * MiB);   // [8192,2048] bf16, 32 MiB
    __hip_bfloat16* h1   = (__hip_bfloat16*)(ws + 80 * MiB);   // [8192,2048] bf16, 32 MiB
    __hip_bfloat16* WaggT= (__hip_bfloat16*)(ws + 112 * MiB);  // [1024,3072] bf16, 6 MiB
    __hip_bfloat16* W1T  = (__hip_bfloat16*)(ws + 118 * MiB);  // [2048,1024] bf16, 4 MiB
    __hip_bfloat16* W2T  = (__hip_bfloat16*)(ws + 122 * MiB);  // [1024,2048] bf16, 4 MiB
    float* pS     = (float*)(ws + 126 * MiB);                   // [64,2048] partials
    float* pS2    = (float*)(ws + 126 * MiB + 512 * 1024);
    float* scale1 = (float*)(ws + 127 * MiB);
    float* shift1 = scale1 + 2048;
    float* scale2 = shift1 + 2048;
    float* shift2 = scale2 + 1024;
    __hip_bfloat16* t2b = h;   // [8192,1024] bf16 (h is dead after GEMM2)

    // merged prep: build_x (blocks 0..8191) + 3 weight transposes (rest)
    prep<<<ROWS + 7168, 256, 0, stream>>>(
        selfv, nbv, mask, xb, W_agg, WaggT, W1, W1T, W2, W2T);

    // GEMM1: h = x @ W_agg + b_agg   (bf16 out, no stats)
    gemm_bt<1, 0><<<512, 512, 0, stream>>>(
        (const short*)xb, (const short*)WaggT, b_agg, h, nullptr, nullptr,
        ROWS, OUTC, XCOLS, 512);

    // GEMM2: t1b = h @ W1 + b1  (bf16 out + BN1 partials; 2 tiles/block)
    gemm_bt<1, 1><<<512, 512, 0, stream>>>(
        (const short*)h, (const short*)W1T, b1, t1b, pS, pS2, ROWS, HIDC, OUTC, 1024);

    // BN1 reduce + apply + ReLU -> h1 (bf16)
    bn_stats2<<<HIDC / 256, 256, 0, stream>>>(pS, pS2, g1, be1, scale1, shift1, HIDC);
    bn_apply_b2b<<<(ROWS * HIDC) / 2048, 256, 0, stream>>>(
        (const short*)t1b, scale1, shift1, (short*)h1, HIDC);

    // GEMM3: t2b = h1 @ W2 + b2  (bf16 out + BN2 partials)
    gemm_bt<1, 1><<<512, 512, 0, stream>>>(
        (const short*)h1, (const short*)W2T, b2, t2b, pS, pS2, ROWS, OUTC, HIDC, 512);

    // BN2 reduce + apply + ReLU -> d_out (f32)
    bn_stats2<<<OUTC / 256, 256, 0, stream>>>(pS, pS2, g2, be2, scale2, shift2, OUTC);
    bn_apply_b2f<<<(ROWS * OUTC) / 2048, 256, 0, stream>>>(
        (const short*)t2b, scale2, shift2, (float*)d_out, OUTC);
}